// Round 7
// baseline (829.908 us; speedup 1.0000x reference)
//
#include <hip/hip_runtime.h>
#include <math.h>
#include <utility>

#define TN 4096
#define XMIN (-8.0f)
#define XMAX (8.0f)

#define GB1 256          // blocks in bucket-hist / bucket-scatter passes
#define MAXBK 1024       // max buckets held in LDS histograms
#define S2_ELEMS 2048
#define S2_BS 256
#define BKN 128          // nodes per bucket

typedef __attribute__((ext_vector_type(8))) short short8;
typedef __attribute__((ext_vector_type(4))) float f32x4;

__device__ __forceinline__ float silu_f(float v) {
    return v / (1.0f + __expf(-v));
}

// bf16 round-to-nearest-even split helpers
__device__ __forceinline__ unsigned short f2bf(float x) {
    unsigned u = __float_as_uint(x);
    return (unsigned short)((u + 0x7FFFu + ((u >> 16) & 1u)) >> 16);
}
__device__ __forceinline__ float bf2f(unsigned short h) {
    return __uint_as_float(((unsigned)h) << 16);
}

#define SPLIT8(w0,w1,w2,w3,w4,w5,w6,w7, H, L) { \
    unsigned short _h0=f2bf(w0),_h1=f2bf(w1),_h2=f2bf(w2),_h3=f2bf(w3), \
                   _h4=f2bf(w4),_h5=f2bf(w5),_h6=f2bf(w6),_h7=f2bf(w7); \
    H = (short8){(short)_h0,(short)_h1,(short)_h2,(short)_h3, \
                 (short)_h4,(short)_h5,(short)_h6,(short)_h7}; \
    L = (short8){(short)f2bf((w0)-bf2f(_h0)),(short)f2bf((w1)-bf2f(_h1)), \
                 (short)f2bf((w2)-bf2f(_h2)),(short)f2bf((w3)-bf2f(_h3)), \
                 (short)f2bf((w4)-bf2f(_h4)),(short)f2bf((w5)-bf2f(_h5)), \
                 (short)f2bf((w6)-bf2f(_h6)),(short)f2bf((w7)-bf2f(_h7))}; }

// B fragment of W (64x64 row-major, B[k][n]): k = kc*32+quad*8+j, n = nt*16+m
#define BFRAG(Wp, kc, nt, H, L) { \
    const float* _p = (Wp) + ((kc)*32 + quad*8)*64 + (nt)*16 + m; \
    SPLIT8(_p[0],_p[64],_p[128],_p[192],_p[256],_p[320],_p[384],_p[448], H, L) }

#define MFMA3(AH, AL, BH, BL, ACC) \
    ACC = __builtin_amdgcn_mfma_f32_16x16x32_bf16(AH, BH, ACC, 0, 0, 0); \
    ACC = __builtin_amdgcn_mfma_f32_16x16x32_bf16(AL, BH, ACC, 0, 0, 0); \
    ACC = __builtin_amdgcn_mfma_f32_16x16x32_bf16(AH, BL, ACC, 0, 0, 0);

// ---------------------------------------------------------------------------
// Tabulate h2(x) = silu( silu(x*W1 + b1) @ W2 + b2 ) on TN grid points.
// ---------------------------------------------------------------------------
__global__ void build_table_k(const float* __restrict__ W1, const float* __restrict__ b1,
                              const float* __restrict__ W2, const float* __restrict__ b2,
                              float* __restrict__ table) {
    int gid  = blockIdx.x * blockDim.x + threadIdx.x;
    int wave = gid >> 6;
    int lane = gid & 63;
    if (wave >= TN) return;
    const float step = (XMAX - XMIN) / (float)(TN - 1);
    float x  = XMIN + step * (float)wave;
    float h1 = silu_f(fmaf(x, W1[lane], b1[lane]));
    float acc = b2[lane];
#pragma unroll
    for (int k = 0; k < 64; ++k) {
        float h1k = __shfl(h1, k, 64);
        acc = fmaf(h1k, W2[k * 64 + lane], acc);
    }
    table[wave * 64 + lane] = silu_f(acc);
}

// ---------------------------------------------------------------------------
// Pass A: per-block LDS histogram of buckets (node >> 7). bin-major output.
// ---------------------------------------------------------------------------
__global__ void bhist_k(const int* __restrict__ row, int* __restrict__ bh,
                        int E, int nbk) {
    __shared__ int h[MAXBK];
    int t = threadIdx.x;
    for (int e = t; e < nbk; e += 256) h[e] = 0;
    __syncthreads();
    for (int i = blockIdx.x * 256 + t; i < E; i += 256 * GB1)
        atomicAdd(&h[row[i] >> 7], 1);
    __syncthreads();
    for (int e = t; e < nbk; e += 256)
        bh[e * GB1 + blockIdx.x] = h[e];
}

// ---------------------------------------------------------------------------
// Scan of bh (M = nbk*GB1 elements), exclusive.
// ---------------------------------------------------------------------------
__global__ void scan2A_k(const int* __restrict__ in, int* __restrict__ out,
                         int* __restrict__ bsum, int n) {
    __shared__ int b0[S2_ELEMS], b1[S2_ELEMS];
    int t = threadIdx.x, base = blockIdx.x * S2_ELEMS;
    for (int e = t; e < S2_ELEMS; e += S2_BS)
        b0[e] = (base + e < n) ? in[base + e] : 0;
    __syncthreads();
    int* src = b0; int* dst = b1;
    for (int d = 1; d < S2_ELEMS; d <<= 1) {
        for (int e = t; e < S2_ELEMS; e += S2_BS)
            dst[e] = src[e] + ((e >= d) ? src[e - d] : 0);
        __syncthreads();
        int* tmp = src; src = dst; dst = tmp;
    }
    for (int e = t; e < S2_ELEMS; e += S2_BS)
        if (base + e < n) out[base + e] = (e == 0) ? 0 : src[e - 1];
    if (t == 0) bsum[blockIdx.x] = src[S2_ELEMS - 1];
}

__global__ void scanB_k(int* __restrict__ bsum, int nb) {
    __shared__ int b0[256], b1[256];
    int t = threadIdx.x;
    b0[t] = (t < nb) ? bsum[t] : 0;
    __syncthreads();
    int* src = b0; int* dst = b1;
    for (int d = 1; d < 256; d <<= 1) {
        dst[t] = src[t] + ((t >= d) ? src[t - d] : 0);
        __syncthreads();
        int* tmp = src; src = dst; dst = tmp;
    }
    if (t < nb) bsum[t] = (t == 0) ? 0 : src[t - 1];
}

__global__ void scan2C_k(int* __restrict__ out, const int* __restrict__ bsum, int n) {
    int i = blockIdx.x * blockDim.x + threadIdx.x;
    if (i < n) out[i] += bsum[i >> 11];       // S2_ELEMS = 2048
}

// ---------------------------------------------------------------------------
// Pass C: scatter packed edges into bucket regions. LDS cursors only.
// packed = local_id(7) | i0(12) | frac(13).
// ---------------------------------------------------------------------------
__global__ void bscatter_k(const int* __restrict__ row, const float* __restrict__ x,
                           const int* __restrict__ bhs, unsigned int* __restrict__ packed,
                           int E, int nbk) {
    __shared__ int cur[MAXBK];
    int t = threadIdx.x;
    for (int e = t; e < nbk; e += 256) cur[e] = bhs[e * GB1 + blockIdx.x];
    __syncthreads();
    const float scale = (float)(TN - 1) / (XMAX - XMIN);
    for (int i = blockIdx.x * 256 + t; i < E; i += 256 * GB1) {
        int   r  = row[i];
        float xv = x[i];
        float tt = fminf(fmaxf((xv - XMIN) * scale, 0.f), (float)(TN - 1) - 0.001f);
        int   i0 = (int)tt;
        unsigned int q = min((unsigned int)((tt - (float)i0) * 8192.0f), 8191u);
        unsigned int pk = ((unsigned int)(r & 127) << 25) | ((unsigned int)i0 << 13) | q;
        int p = atomicAdd(&cur[r >> 7], 1);
        packed[p] = pk;
    }
}

// ---------------------------------------------------------------------------
// Pass D: edge-parallel bucket aggregation. Block = 1 bucket (128 nodes).
// Thread = (edge, 16-channel quadrant): direct packed load (no shuffle),
// 8x float4 table loads, lerp, 16 LDS atomicAdd (fire-and-forget -> no
// loop-carried dependence; rounds 5/6 serialized per-wave edge chains).
// agg stride 65 floats: different nodes land on different banks.
// ---------------------------------------------------------------------------
__global__ __launch_bounds__(256, 4)
void agg_k(const unsigned int* __restrict__ packed, const int* __restrict__ bhs,
           const float* __restrict__ table, float* __restrict__ aggOut,
           int N, int E, int nbk) {
    __shared__ float agg[BKN * 65];
    int t = threadIdx.x;
    int b = blockIdx.x;
    for (int i = t; i < BKN * 65; i += 256) agg[i] = 0.f;
    __syncthreads();

    int s  = bhs[b * GB1];
    int e_ = (b + 1 < nbk) ? bhs[(b + 1) * GB1] : E;
    int cnt = e_ - s;
    int sub = t & 3;

    for (int e = t >> 2; e < cnt; e += 64) {
        unsigned int pk = packed[s + e];
        int   nl = pk >> 25;
        int   i0 = (pk >> 13) & 0xFFFu;
        float f  = (float)(pk & 0x1FFFu) * (1.0f / 8192.0f);
        const float4* r0 = (const float4*)(table + ((size_t)i0 << 6)) + sub * 4;
        float4 u0 = r0[0], u1 = r0[1], u2 = r0[2], u3 = r0[3];
        float4 v0 = r0[16], v1 = r0[17], v2 = r0[18], v3 = r0[19];
        float* d = agg + nl * 65 + sub * 16;
        atomicAdd(d + 0,  fmaf(f, v0.x - u0.x, u0.x));
        atomicAdd(d + 1,  fmaf(f, v0.y - u0.y, u0.y));
        atomicAdd(d + 2,  fmaf(f, v0.z - u0.z, u0.z));
        atomicAdd(d + 3,  fmaf(f, v0.w - u0.w, u0.w));
        atomicAdd(d + 4,  fmaf(f, v1.x - u1.x, u1.x));
        atomicAdd(d + 5,  fmaf(f, v1.y - u1.y, u1.y));
        atomicAdd(d + 6,  fmaf(f, v1.z - u1.z, u1.z));
        atomicAdd(d + 7,  fmaf(f, v1.w - u1.w, u1.w));
        atomicAdd(d + 8,  fmaf(f, v2.x - u2.x, u2.x));
        atomicAdd(d + 9,  fmaf(f, v2.y - u2.y, u2.y));
        atomicAdd(d + 10, fmaf(f, v2.z - u2.z, u2.z));
        atomicAdd(d + 11, fmaf(f, v2.w - u2.w, u2.w));
        atomicAdd(d + 12, fmaf(f, v3.x - u3.x, u3.x));
        atomicAdd(d + 13, fmaf(f, v3.y - u3.y, u3.y));
        atomicAdd(d + 14, fmaf(f, v3.z - u3.z, u3.z));
        atomicAdd(d + 15, fmaf(f, v3.w - u3.w, u3.w));
    }
    __syncthreads();

    for (int i = t; i < BKN * 64; i += 256) {
        int r = i >> 6, c = i & 63;
        int n = (b << 7) + r;
        if (n < N) aggOut[(size_t)n * 64 + c] = agg[r * 65 + c];
    }
}

// ---------------------------------------------------------------------------
// Pass E: node MLP via bf16 MFMA with hi/lo error compensation (err ~2^-15).
// Wave = 16 nodes; in-place on h (each block touches only its own rows).
// C->A inter-layer transform through a per-wave LDS tile (stride 68: 2-way
// bank aliasing only). Weights live in named short8 fragments (no indexed
// arrays -> no spill trap).
// ---------------------------------------------------------------------------
__global__ __launch_bounds__(256, 1)
void mlp_k(const float* __restrict__ W3, const float* __restrict__ b3,
           const float* __restrict__ W4, const float* __restrict__ b4,
           float* __restrict__ h, int N) {
    __shared__ float gt[4][16 * 68];
    int t = threadIdx.x, lane = t & 63, wid = t >> 6;
    int m = lane & 15, quad = lane >> 4;
    long r0 = (long)blockIdx.x * 64 + wid * 16;
    if (r0 >= N) return;

    // W3 / W4 fragments (hi/lo), names: B<layer><h/l><nt><kc>
    short8 B3h00,B3l00,B3h01,B3l01, B3h10,B3l10,B3h11,B3l11;
    short8 B3h20,B3l20,B3h21,B3l21, B3h30,B3l30,B3h31,B3l31;
    short8 B4h00,B4l00,B4h01,B4l01, B4h10,B4l10,B4h11,B4l11;
    short8 B4h20,B4l20,B4h21,B4l21, B4h30,B4l30,B4h31,B4l31;
    BFRAG(W3, 0, 0, B3h00, B3l00)  BFRAG(W3, 1, 0, B3h01, B3l01)
    BFRAG(W3, 0, 1, B3h10, B3l10)  BFRAG(W3, 1, 1, B3h11, B3l11)
    BFRAG(W3, 0, 2, B3h20, B3l20)  BFRAG(W3, 1, 2, B3h21, B3l21)
    BFRAG(W3, 0, 3, B3h30, B3l30)  BFRAG(W3, 1, 3, B3h31, B3l31)
    BFRAG(W4, 0, 0, B4h00, B4l00)  BFRAG(W4, 1, 0, B4h01, B4l01)
    BFRAG(W4, 0, 1, B4h10, B4l10)  BFRAG(W4, 1, 1, B4h11, B4l11)
    BFRAG(W4, 0, 2, B4h20, B4l20)  BFRAG(W4, 1, 2, B4h21, B4l21)
    BFRAG(W4, 0, 3, B4h30, B4l30)  BFRAG(W4, 1, 3, B4h31, B4l31)

    // A fragments from agg rows: A[m][k], k = kc*32 + quad*8 + j
    long ra = r0 + m; if (ra > N - 1) ra = N - 1;
    const float* ap = h + ra * 64 + quad * 8;
    float4 p0 = *(const float4*)(ap);       float4 p1 = *(const float4*)(ap + 4);
    float4 p2 = *(const float4*)(ap + 32);  float4 p3 = *(const float4*)(ap + 36);
    short8 Ah0, Al0, Ah1, Al1;
    SPLIT8(p0.x,p0.y,p0.z,p0.w,p1.x,p1.y,p1.z,p1.w, Ah0, Al0)
    SPLIT8(p2.x,p2.y,p2.z,p2.w,p3.x,p3.y,p3.z,p3.w, Ah1, Al1)

    // layer 1
    f32x4 acc0 = {0.f,0.f,0.f,0.f}, acc1 = {0.f,0.f,0.f,0.f};
    f32x4 acc2 = {0.f,0.f,0.f,0.f}, acc3 = {0.f,0.f,0.f,0.f};
    MFMA3(Ah0, Al0, B3h00, B3l00, acc0)  MFMA3(Ah1, Al1, B3h01, B3l01, acc0)
    MFMA3(Ah0, Al0, B3h10, B3l10, acc1)  MFMA3(Ah1, Al1, B3h11, B3l11, acc1)
    MFMA3(Ah0, Al0, B3h20, B3l20, acc2)  MFMA3(Ah1, Al1, B3h21, B3l21, acc2)
    MFMA3(Ah0, Al0, B3h30, B3l30, acc3)  MFMA3(Ah1, Al1, B3h31, B3l31, acc3)

    // bias + silu, write to LDS tile in C layout: row=quad*4+reg, col=nt*16+m
    float* g = gt[wid];
    {
        float bv = b3[0*16 + m];
        g[(quad*4+0)*68 + 0*16 + m] = silu_f(acc0.x + bv);
        g[(quad*4+1)*68 + 0*16 + m] = silu_f(acc0.y + bv);
        g[(quad*4+2)*68 + 0*16 + m] = silu_f(acc0.z + bv);
        g[(quad*4+3)*68 + 0*16 + m] = silu_f(acc0.w + bv);
    }
    {
        float bv = b3[1*16 + m];
        g[(quad*4+0)*68 + 1*16 + m] = silu_f(acc1.x + bv);
        g[(quad*4+1)*68 + 1*16 + m] = silu_f(acc1.y + bv);
        g[(quad*4+2)*68 + 1*16 + m] = silu_f(acc1.z + bv);
        g[(quad*4+3)*68 + 1*16 + m] = silu_f(acc1.w + bv);
    }
    {
        float bv = b3[2*16 + m];
        g[(quad*4+0)*68 + 2*16 + m] = silu_f(acc2.x + bv);
        g[(quad*4+1)*68 + 2*16 + m] = silu_f(acc2.y + bv);
        g[(quad*4+2)*68 + 2*16 + m] = silu_f(acc2.z + bv);
        g[(quad*4+3)*68 + 2*16 + m] = silu_f(acc2.w + bv);
    }
    {
        float bv = b3[3*16 + m];
        g[(quad*4+0)*68 + 3*16 + m] = silu_f(acc3.x + bv);
        g[(quad*4+1)*68 + 3*16 + m] = silu_f(acc3.y + bv);
        g[(quad*4+2)*68 + 3*16 + m] = silu_f(acc3.z + bv);
        g[(quad*4+3)*68 + 3*16 + m] = silu_f(acc3.w + bv);
    }
    __syncthreads();   // order LDS writes before reads (wave-private region, but safe)

    // layer-2 A fragments from g: A[m][k] = g[m][kc*32 + quad*8 + j]
    const float* gp = g + m * 68 + quad * 8;
    float4 q0 = *(const float4*)(gp);       float4 q1 = *(const float4*)(gp + 4);
    float4 q2 = *(const float4*)(gp + 32);  float4 q3 = *(const float4*)(gp + 36);
    short8 Gh0, Gl0, Gh1, Gl1;
    SPLIT8(q0.x,q0.y,q0.z,q0.w,q1.x,q1.y,q1.z,q1.w, Gh0, Gl0)
    SPLIT8(q2.x,q2.y,q2.z,q2.w,q3.x,q3.y,q3.z,q3.w, Gh1, Gl1)

    f32x4 o0 = {0.f,0.f,0.f,0.f}, o1 = {0.f,0.f,0.f,0.f};
    f32x4 o2 = {0.f,0.f,0.f,0.f}, o3 = {0.f,0.f,0.f,0.f};
    MFMA3(Gh0, Gl0, B4h00, B4l00, o0)  MFMA3(Gh1, Gl1, B4h01, B4l01, o0)
    MFMA3(Gh0, Gl0, B4h10, B4l10, o1)  MFMA3(Gh1, Gl1, B4h11, B4l11, o1)
    MFMA3(Gh0, Gl0, B4h20, B4l20, o2)  MFMA3(Gh1, Gl1, B4h21, B4l21, o2)
    MFMA3(Gh0, Gl0, B4h30, B4l30, o3)  MFMA3(Gh1, Gl1, B4h31, B4l31, o3)

    long rw = r0 + quad * 4;
    float c0 = b4[0*16 + m], c1 = b4[1*16 + m], c2 = b4[2*16 + m], c3 = b4[3*16 + m];
    if (rw + 0 < N) { float* o = h + (rw+0)*64;
        o[ 0+m]=o0.x+c0; o[16+m]=o1.x+c1; o[32+m]=o2.x+c2; o[48+m]=o3.x+c3; }
    if (rw + 1 < N) { float* o = h + (rw+1)*64;
        o[ 0+m]=o0.y+c0; o[16+m]=o1.y+c1; o[32+m]=o2.y+c2; o[48+m]=o3.y+c3; }
    if (rw + 2 < N) { float* o = h + (rw+2)*64;
        o[ 0+m]=o0.z+c0; o[16+m]=o1.z+c1; o[32+m]=o2.z+c2; o[48+m]=o3.z+c3; }
    if (rw + 3 < N) { float* o = h + (rw+3)*64;
        o[ 0+m]=o0.w+c0; o[16+m]=o1.w+c1; o[32+m]=o2.w+c2; o[48+m]=o3.w+c3; }
}

// ------------------------- fallback path (atomic scatter) -------------------
__global__ void zero_k(float4* __restrict__ p, int n4) {
    int i = blockIdx.x * blockDim.x + threadIdx.x;
    int stride = gridDim.x * blockDim.x;
    float4 z = make_float4(0.f, 0.f, 0.f, 0.f);
    for (; i < n4; i += stride) p[i] = z;
}

__global__ void edge_k(const int* __restrict__ row, const float* __restrict__ xarr,
                       const float* __restrict__ table, float* __restrict__ agg, int E) {
    int gid    = blockIdx.x * blockDim.x + threadIdx.x;
    int lane   = gid & 63;
    int wave   = gid >> 6;
    int nwaves = (gridDim.x * blockDim.x) >> 6;
    const float scale = (float)(TN - 1) / (XMAX - XMIN);
    for (int e = wave; e < E; e += nwaves) {
        float x = xarr[e];
        int   r = row[e];
        float t = fminf(fmaxf((x - XMIN) * scale, 0.0f), (float)(TN - 1) - 0.001f);
        int   i0 = (int)t;
        float f  = t - (float)i0;
        const float* tp = table + (size_t)i0 * 64 + lane;
        float v0 = tp[0];
        float v1 = tp[64];
        atomicAdd(agg + (size_t)r * 64 + lane, fmaf(f, v1 - v0, v0));
    }
}

// ---------------------------------------------------------------------------
extern "C" void kernel_launch(void* const* d_in, const int* in_sizes, int n_in,
                              void* d_out, int out_size, void* d_ws, size_t ws_size,
                              hipStream_t stream) {
    const int*   edge_index = (const int*)  d_in[0];   // [2, E] int32; row = first E
    const float* edge_attr  = (const float*)d_in[1];   // [E, 1]
    const float* W1 = (const float*)d_in[2];
    const float* b1 = (const float*)d_in[3];
    const float* W2 = (const float*)d_in[4];
    const float* b2 = (const float*)d_in[5];
    const float* W3 = (const float*)d_in[6];
    const float* b3 = (const float*)d_in[7];
    const float* W4 = (const float*)d_in[8];
    const float* b4 = (const float*)d_in[9];

    float* out = (float*)d_out;                        // [N, 64]
    const int E   = in_sizes[1];
    const int N   = out_size / 64;
    const int nbk = (N + 127) >> 7;                    // 782 buckets of 128 nodes
    const int M   = nbk * GB1;
    const int nsb = (M + S2_ELEMS - 1) / S2_ELEMS;
    const int nmb = (N + 63) / 64;                     // mlp blocks

    // workspace carve-up (256 B aligned)
    char* ws = (char*)d_ws;
    size_t off = 0;
    auto carve = [&](size_t bytes) { size_t r = off; off = (off + bytes + 255) & ~(size_t)255; return r; };
    size_t tableOff = carve((size_t)TN * 64 * 4);      // 1 MiB
    size_t bhOff    = carve((size_t)M * 4);            // ~800 KiB
    size_t bsumOff  = carve((size_t)nsb * 4);
    size_t pkOff    = carve((size_t)E * 4);            // 6.4 MiB
    bool fits = (off <= ws_size) && (nbk <= MAXBK) && (nsb <= 256);

    float* table = (float*)(ws + tableOff);

    build_table_k<<<TN / 4, 256, 0, stream>>>(W1, b1, W2, b2, table);

    if (fits) {
        int* bh   = (int*)(ws + bhOff);
        int* bsum = (int*)(ws + bsumOff);
        unsigned int* packed = (unsigned int*)(ws + pkOff);

        bhist_k  <<<GB1, 256, 0, stream>>>(edge_index, bh, E, nbk);
        scan2A_k <<<nsb, S2_BS, 0, stream>>>(bh, bh, bsum, M);
        scanB_k  <<<1, 256, 0, stream>>>(bsum, nsb);
        scan2C_k <<<(M + 255) / 256, 256, 0, stream>>>(bh, bsum, M);
        bscatter_k<<<GB1, 256, 0, stream>>>(edge_index, edge_attr, bh, packed, E, nbk);
        agg_k    <<<nbk, 256, 0, stream>>>(packed, bh, table, out, N, E, nbk);
        mlp_k    <<<nmb, 256, 0, stream>>>(W3, b3, W4, b4, out, N);
    } else {
        zero_k<<<4096, 256, 0, stream>>>((float4*)out, (N * 64) / 4);
        edge_k<<<8192, 256, 0, stream>>>(edge_index, edge_attr, table, out, E);
        mlp_k <<<nmb, 256, 0, stream>>>(W3, b3, W4, b4, out, N);
    }
}

// Round 8
// 210.843 us; speedup vs baseline: 3.9361x; 3.9361x over previous
//
#include <hip/hip_runtime.h>
#include <math.h>
#include <utility>

#define TN 4096
#define XMIN (-8.0f)
#define XMAX (8.0f)

#define GB1 256          // blocks in bucket-hist / bucket-scatter passes
#define MAXBK 1024       // max buckets held in LDS histograms
#define S2_ELEMS 2048
#define S2_BS 256
#define BKN 128          // nodes per bucket
#define BKCAP 3072       // max edges/bucket in LDS (mean 2048, sd ~45 -> 22 sigma)

typedef __attribute__((ext_vector_type(8))) short short8;
typedef __attribute__((ext_vector_type(4))) float f32x4;

__device__ __forceinline__ float silu_f(float v) {
    return v / (1.0f + __expf(-v));
}

// bf16 round-to-nearest-even split helpers
__device__ __forceinline__ unsigned short f2bf(float x) {
    unsigned u = __float_as_uint(x);
    return (unsigned short)((u + 0x7FFFu + ((u >> 16) & 1u)) >> 16);
}
__device__ __forceinline__ float bf2f(unsigned short h) {
    return __uint_as_float(((unsigned)h) << 16);
}

#define SPLIT8(w0,w1,w2,w3,w4,w5,w6,w7, H, L) { \
    unsigned short _h0=f2bf(w0),_h1=f2bf(w1),_h2=f2bf(w2),_h3=f2bf(w3), \
                   _h4=f2bf(w4),_h5=f2bf(w5),_h6=f2bf(w6),_h7=f2bf(w7); \
    H = (short8){(short)_h0,(short)_h1,(short)_h2,(short)_h3, \
                 (short)_h4,(short)_h5,(short)_h6,(short)_h7}; \
    L = (short8){(short)f2bf((w0)-bf2f(_h0)),(short)f2bf((w1)-bf2f(_h1)), \
                 (short)f2bf((w2)-bf2f(_h2)),(short)f2bf((w3)-bf2f(_h3)), \
                 (short)f2bf((w4)-bf2f(_h4)),(short)f2bf((w5)-bf2f(_h5)), \
                 (short)f2bf((w6)-bf2f(_h6)),(short)f2bf((w7)-bf2f(_h7))}; }

// B fragment of W (64x64 row-major, B[k][n]): k = kc*32+quad*8+j, n = nt*16+m
#define BFRAG(Wp, kc, nt, H, L) { \
    const float* _p = (Wp) + ((kc)*32 + quad*8)*64 + (nt)*16 + m; \
    SPLIT8(_p[0],_p[64],_p[128],_p[192],_p[256],_p[320],_p[384],_p[448], H, L) }

#define MFMA3(AH, AL, BH, BL, ACC) \
    ACC = __builtin_amdgcn_mfma_f32_16x16x32_bf16(AH, BH, ACC, 0, 0, 0); \
    ACC = __builtin_amdgcn_mfma_f32_16x16x32_bf16(AL, BH, ACC, 0, 0, 0); \
    ACC = __builtin_amdgcn_mfma_f32_16x16x32_bf16(AH, BL, ACC, 0, 0, 0);

// ---------------------------------------------------------------------------
// Tabulate h2(x) = silu( silu(x*W1 + b1) @ W2 + b2 ) on TN grid points.
// ---------------------------------------------------------------------------
__global__ void build_table_k(const float* __restrict__ W1, const float* __restrict__ b1,
                              const float* __restrict__ W2, const float* __restrict__ b2,
                              float* __restrict__ table) {
    int gid  = blockIdx.x * blockDim.x + threadIdx.x;
    int wave = gid >> 6;
    int lane = gid & 63;
    if (wave >= TN) return;
    const float step = (XMAX - XMIN) / (float)(TN - 1);
    float x  = XMIN + step * (float)wave;
    float h1 = silu_f(fmaf(x, W1[lane], b1[lane]));
    float acc = b2[lane];
#pragma unroll
    for (int k = 0; k < 64; ++k) {
        float h1k = __shfl(h1, k, 64);
        acc = fmaf(h1k, W2[k * 64 + lane], acc);
    }
    table[wave * 64 + lane] = silu_f(acc);
}

// ---------------------------------------------------------------------------
// Pass A: per-block LDS histogram of buckets (node >> 7). bin-major output.
// ---------------------------------------------------------------------------
__global__ void bhist_k(const int* __restrict__ row, int* __restrict__ bh,
                        int E, int nbk) {
    __shared__ int h[MAXBK];
    int t = threadIdx.x;
    for (int e = t; e < nbk; e += 256) h[e] = 0;
    __syncthreads();
    for (int i = blockIdx.x * 256 + t; i < E; i += 256 * GB1)
        atomicAdd(&h[row[i] >> 7], 1);
    __syncthreads();
    for (int e = t; e < nbk; e += 256)
        bh[e * GB1 + blockIdx.x] = h[e];
}

// ---------------------------------------------------------------------------
// Scan of bh (M = nbk*GB1 elements), exclusive.
// ---------------------------------------------------------------------------
__global__ void scan2A_k(const int* __restrict__ in, int* __restrict__ out,
                         int* __restrict__ bsum, int n) {
    __shared__ int b0[S2_ELEMS], b1[S2_ELEMS];
    int t = threadIdx.x, base = blockIdx.x * S2_ELEMS;
    for (int e = t; e < S2_ELEMS; e += S2_BS)
        b0[e] = (base + e < n) ? in[base + e] : 0;
    __syncthreads();
    int* src = b0; int* dst = b1;
    for (int d = 1; d < S2_ELEMS; d <<= 1) {
        for (int e = t; e < S2_ELEMS; e += S2_BS)
            dst[e] = src[e] + ((e >= d) ? src[e - d] : 0);
        __syncthreads();
        int* tmp = src; src = dst; dst = tmp;
    }
    for (int e = t; e < S2_ELEMS; e += S2_BS)
        if (base + e < n) out[base + e] = (e == 0) ? 0 : src[e - 1];
    if (t == 0) bsum[blockIdx.x] = src[S2_ELEMS - 1];
}

__global__ void scanB_k(int* __restrict__ bsum, int nb) {
    __shared__ int b0[256], b1[256];
    int t = threadIdx.x;
    b0[t] = (t < nb) ? bsum[t] : 0;
    __syncthreads();
    int* src = b0; int* dst = b1;
    for (int d = 1; d < 256; d <<= 1) {
        dst[t] = src[t] + ((t >= d) ? src[t - d] : 0);
        __syncthreads();
        int* tmp = src; src = dst; dst = tmp;
    }
    if (t < nb) bsum[t] = (t == 0) ? 0 : src[t - 1];
}

__global__ void scan2C_k(int* __restrict__ out, const int* __restrict__ bsum, int n) {
    int i = blockIdx.x * blockDim.x + threadIdx.x;
    if (i < n) out[i] += bsum[i >> 11];       // S2_ELEMS = 2048
}

// ---------------------------------------------------------------------------
// Pass C: scatter packed edges into bucket regions. LDS int cursors (native).
// packed = local_id(7) | i0(12) | frac(13).
// ---------------------------------------------------------------------------
__global__ void bscatter_k(const int* __restrict__ row, const float* __restrict__ x,
                           const int* __restrict__ bhs, unsigned int* __restrict__ packed,
                           int E, int nbk) {
    __shared__ int cur[MAXBK];
    int t = threadIdx.x;
    for (int e = t; e < nbk; e += 256) cur[e] = bhs[e * GB1 + blockIdx.x];
    __syncthreads();
    const float scale = (float)(TN - 1) / (XMAX - XMIN);
    for (int i = blockIdx.x * 256 + t; i < E; i += 256 * GB1) {
        int   r  = row[i];
        float xv = x[i];
        float tt = fminf(fmaxf((xv - XMIN) * scale, 0.f), (float)(TN - 1) - 0.001f);
        int   i0 = (int)tt;
        unsigned int q = min((unsigned int)((tt - (float)i0) * 8192.0f), 8191u);
        unsigned int pk = ((unsigned int)(r & 127) << 25) | ((unsigned int)i0 << 13) | q;
        int p = atomicAdd(&cur[r >> 7], 1);
        packed[p] = pk;
    }
}

// ---------------------------------------------------------------------------
// Pass D: within-bucket counting sort (LDS int atomics, native) + per-node-
// wave gather with REGISTER accumulation. No fp atomics anywhere (round 7's
// LDS float atomicAdd = CAS loop = 680 us disaster).
// Block = 1 bucket (128 nodes), 256 threads = 4 waves. No MLP weights here
// (VGPR <= 64 -> LDS-bound occupancy ~8 blocks/CU = 32 waves/CU for latency
// hiding; round 6 carried weights -> spill + 1.7 blocks/CU).
// Phase 2: wave = node; edge words read via uniform-address ds_read
// (broadcast); 4-edge unroll = 8 independent L2 table loads in flight.
// ---------------------------------------------------------------------------
__global__ __launch_bounds__(256, 8)
void gather_k(const unsigned int* __restrict__ packed, const int* __restrict__ bhs,
              const float* __restrict__ table, float* __restrict__ aggOut,
              int N, int E, int nbk) {
    __shared__ unsigned int srt[BKCAP];
    __shared__ int hist[BKN + 1];
    __shared__ int curs[BKN];
    int t = threadIdx.x, lane = t & 63, wid = t >> 6;
    int b = blockIdx.x;

    int s  = bhs[b * GB1];
    int e_ = (b + 1 < nbk) ? bhs[(b + 1) * GB1] : E;
    int cnt = min(e_ - s, BKCAP);          // 22-sigma clamp; never hit

    for (int i = t; i <= BKN; i += 256) hist[i] = 0;
    __syncthreads();
    for (int i = t; i < cnt; i += 256)
        atomicAdd(&hist[packed[s + i] >> 25], 1);   // int LDS atomic: native
    __syncthreads();

    if (wid == 0) {                        // exclusive scan of 128 counts
        int c0 = hist[lane], c1 = hist[64 + lane];
        int s0 = c0, s1 = c1;
#pragma unroll
        for (int d = 1; d < 64; d <<= 1) {
            int u0 = __shfl_up(s0, d, 64);
            int u1 = __shfl_up(s1, d, 64);
            if (lane >= d) { s0 += u0; s1 += u1; }
        }
        int tot0 = __shfl(s0, 63, 64);
        hist[lane]      = s0 - c0;         curs[lane]      = s0 - c0;
        hist[64 + lane] = tot0 + s1 - c1;  curs[64 + lane] = tot0 + s1 - c1;
        if (lane == 63) hist[BKN] = tot0 + s1;
    }
    __syncthreads();

    for (int i = t; i < cnt; i += 256) {
        unsigned int p = packed[s + i];    // L2-warm reread
        int pos = atomicAdd(&curs[p >> 25], 1);
        srt[pos] = p;
    }
    __syncthreads();

    for (int nl = wid; nl < BKN; nl += 4) {
        int n = (b << 7) + nl;
        if (n >= N) break;
        int beg = hist[nl], dn = hist[nl + 1] - beg;
        float a0 = 0.f, a1 = 0.f, a2 = 0.f, a3 = 0.f;
        int j = 0;
        for (; j + 4 <= dn; j += 4) {
            unsigned int p0 = srt[beg + j + 0];    // uniform addr -> broadcast
            unsigned int p1 = srt[beg + j + 1];
            unsigned int p2 = srt[beg + j + 2];
            unsigned int p3 = srt[beg + j + 3];
            const float* r0 = table + (((p0 >> 13) & 0xFFFu) << 6) + lane;
            const float* r1 = table + (((p1 >> 13) & 0xFFFu) << 6) + lane;
            const float* r2 = table + (((p2 >> 13) & 0xFFFu) << 6) + lane;
            const float* r3 = table + (((p3 >> 13) & 0xFFFu) << 6) + lane;
            float u0 = r0[0], v0 = r0[64];
            float u1 = r1[0], v1 = r1[64];
            float u2 = r2[0], v2 = r2[64];
            float u3 = r3[0], v3 = r3[64];
            float f0 = (float)(p0 & 0x1FFFu) * (1.0f / 8192.0f);
            float f1 = (float)(p1 & 0x1FFFu) * (1.0f / 8192.0f);
            float f2 = (float)(p2 & 0x1FFFu) * (1.0f / 8192.0f);
            float f3 = (float)(p3 & 0x1FFFu) * (1.0f / 8192.0f);
            a0 = fmaf(f0, v0 - u0, a0 + u0);
            a1 = fmaf(f1, v1 - u1, a1 + u1);
            a2 = fmaf(f2, v2 - u2, a2 + u2);
            a3 = fmaf(f3, v3 - u3, a3 + u3);
        }
        for (; j < dn; ++j) {
            unsigned int p0 = srt[beg + j];
            const float* r0 = table + (((p0 >> 13) & 0xFFFu) << 6) + lane;
            float u0 = r0[0], v0 = r0[64];
            float f0 = (float)(p0 & 0x1FFFu) * (1.0f / 8192.0f);
            a0 = fmaf(f0, v0 - u0, a0 + u0);
        }
        aggOut[(size_t)n * 64 + lane] = (a0 + a1) + (a2 + a3);
    }
}

// ---------------------------------------------------------------------------
// Pass E: node MLP via bf16 MFMA with hi/lo error compensation (err ~2^-15).
// Wave = 16 nodes; in-place on h. Weights in named short8 fragments.
// ---------------------------------------------------------------------------
__global__ __launch_bounds__(256, 1)
void mlp_k(const float* __restrict__ W3, const float* __restrict__ b3,
           const float* __restrict__ W4, const float* __restrict__ b4,
           float* __restrict__ h, int N) {
    __shared__ float gt[4][16 * 68];
    int t = threadIdx.x, lane = t & 63, wid = t >> 6;
    int m = lane & 15, quad = lane >> 4;
    long r0 = (long)blockIdx.x * 64 + wid * 16;
    if (r0 >= N) return;

    short8 B3h00,B3l00,B3h01,B3l01, B3h10,B3l10,B3h11,B3l11;
    short8 B3h20,B3l20,B3h21,B3l21, B3h30,B3l30,B3h31,B3l31;
    short8 B4h00,B4l00,B4h01,B4l01, B4h10,B4l10,B4h11,B4l11;
    short8 B4h20,B4l20,B4h21,B4l21, B4h30,B4l30,B4h31,B4l31;
    BFRAG(W3, 0, 0, B3h00, B3l00)  BFRAG(W3, 1, 0, B3h01, B3l01)
    BFRAG(W3, 0, 1, B3h10, B3l10)  BFRAG(W3, 1, 1, B3h11, B3l11)
    BFRAG(W3, 0, 2, B3h20, B3l20)  BFRAG(W3, 1, 2, B3h21, B3l21)
    BFRAG(W3, 0, 3, B3h30, B3l30)  BFRAG(W3, 1, 3, B3h31, B3l31)
    BFRAG(W4, 0, 0, B4h00, B4l00)  BFRAG(W4, 1, 0, B4h01, B4l01)
    BFRAG(W4, 0, 1, B4h10, B4l10)  BFRAG(W4, 1, 1, B4h11, B4l11)
    BFRAG(W4, 0, 2, B4h20, B4l20)  BFRAG(W4, 1, 2, B4h21, B4l21)
    BFRAG(W4, 0, 3, B4h30, B4l30)  BFRAG(W4, 1, 3, B4h31, B4l31)

    long ra = r0 + m; if (ra > N - 1) ra = N - 1;
    const float* ap = h + ra * 64 + quad * 8;
    float4 p0 = *(const float4*)(ap);       float4 p1 = *(const float4*)(ap + 4);
    float4 p2 = *(const float4*)(ap + 32);  float4 p3 = *(const float4*)(ap + 36);
    short8 Ah0, Al0, Ah1, Al1;
    SPLIT8(p0.x,p0.y,p0.z,p0.w,p1.x,p1.y,p1.z,p1.w, Ah0, Al0)
    SPLIT8(p2.x,p2.y,p2.z,p2.w,p3.x,p3.y,p3.z,p3.w, Ah1, Al1)

    f32x4 acc0 = {0.f,0.f,0.f,0.f}, acc1 = {0.f,0.f,0.f,0.f};
    f32x4 acc2 = {0.f,0.f,0.f,0.f}, acc3 = {0.f,0.f,0.f,0.f};
    MFMA3(Ah0, Al0, B3h00, B3l00, acc0)  MFMA3(Ah1, Al1, B3h01, B3l01, acc0)
    MFMA3(Ah0, Al0, B3h10, B3l10, acc1)  MFMA3(Ah1, Al1, B3h11, B3l11, acc1)
    MFMA3(Ah0, Al0, B3h20, B3l20, acc2)  MFMA3(Ah1, Al1, B3h21, B3l21, acc2)
    MFMA3(Ah0, Al0, B3h30, B3l30, acc3)  MFMA3(Ah1, Al1, B3h31, B3l31, acc3)

    float* g = gt[wid];
    {
        float bv = b3[0*16 + m];
        g[(quad*4+0)*68 + 0*16 + m] = silu_f(acc0.x + bv);
        g[(quad*4+1)*68 + 0*16 + m] = silu_f(acc0.y + bv);
        g[(quad*4+2)*68 + 0*16 + m] = silu_f(acc0.z + bv);
        g[(quad*4+3)*68 + 0*16 + m] = silu_f(acc0.w + bv);
    }
    {
        float bv = b3[1*16 + m];
        g[(quad*4+0)*68 + 1*16 + m] = silu_f(acc1.x + bv);
        g[(quad*4+1)*68 + 1*16 + m] = silu_f(acc1.y + bv);
        g[(quad*4+2)*68 + 1*16 + m] = silu_f(acc1.z + bv);
        g[(quad*4+3)*68 + 1*16 + m] = silu_f(acc1.w + bv);
    }
    {
        float bv = b3[2*16 + m];
        g[(quad*4+0)*68 + 2*16 + m] = silu_f(acc2.x + bv);
        g[(quad*4+1)*68 + 2*16 + m] = silu_f(acc2.y + bv);
        g[(quad*4+2)*68 + 2*16 + m] = silu_f(acc2.z + bv);
        g[(quad*4+3)*68 + 2*16 + m] = silu_f(acc2.w + bv);
    }
    {
        float bv = b3[3*16 + m];
        g[(quad*4+0)*68 + 3*16 + m] = silu_f(acc3.x + bv);
        g[(quad*4+1)*68 + 3*16 + m] = silu_f(acc3.y + bv);
        g[(quad*4+2)*68 + 3*16 + m] = silu_f(acc3.z + bv);
        g[(quad*4+3)*68 + 3*16 + m] = silu_f(acc3.w + bv);
    }
    __syncthreads();

    const float* gp = g + m * 68 + quad * 8;
    float4 q0 = *(const float4*)(gp);       float4 q1 = *(const float4*)(gp + 4);
    float4 q2 = *(const float4*)(gp + 32);  float4 q3 = *(const float4*)(gp + 36);
    short8 Gh0, Gl0, Gh1, Gl1;
    SPLIT8(q0.x,q0.y,q0.z,q0.w,q1.x,q1.y,q1.z,q1.w, Gh0, Gl0)
    SPLIT8(q2.x,q2.y,q2.z,q2.w,q3.x,q3.y,q3.z,q3.w, Gh1, Gl1)

    f32x4 o0 = {0.f,0.f,0.f,0.f}, o1 = {0.f,0.f,0.f,0.f};
    f32x4 o2 = {0.f,0.f,0.f,0.f}, o3 = {0.f,0.f,0.f,0.f};
    MFMA3(Gh0, Gl0, B4h00, B4l00, o0)  MFMA3(Gh1, Gl1, B4h01, B4l01, o0)
    MFMA3(Gh0, Gl0, B4h10, B4l10, o1)  MFMA3(Gh1, Gl1, B4h11, B4l11, o1)
    MFMA3(Gh0, Gl0, B4h20, B4l20, o2)  MFMA3(Gh1, Gl1, B4h21, B4l21, o2)
    MFMA3(Gh0, Gl0, B4h30, B4l30, o3)  MFMA3(Gh1, Gl1, B4h31, B4l31, o3)

    long rw = r0 + quad * 4;
    float c0 = b4[0*16 + m], c1 = b4[1*16 + m], c2 = b4[2*16 + m], c3 = b4[3*16 + m];
    if (rw + 0 < N) { float* o = h + (rw+0)*64;
        o[ 0+m]=o0.x+c0; o[16+m]=o1.x+c1; o[32+m]=o2.x+c2; o[48+m]=o3.x+c3; }
    if (rw + 1 < N) { float* o = h + (rw+1)*64;
        o[ 0+m]=o0.y+c0; o[16+m]=o1.y+c1; o[32+m]=o2.y+c2; o[48+m]=o3.y+c3; }
    if (rw + 2 < N) { float* o = h + (rw+2)*64;
        o[ 0+m]=o0.z+c0; o[16+m]=o1.z+c1; o[32+m]=o2.z+c2; o[48+m]=o3.z+c3; }
    if (rw + 3 < N) { float* o = h + (rw+3)*64;
        o[ 0+m]=o0.w+c0; o[16+m]=o1.w+c1; o[32+m]=o2.w+c2; o[48+m]=o3.w+c3; }
}

// ------------------------- fallback path (atomic scatter) -------------------
__global__ void zero_k(float4* __restrict__ p, int n4) {
    int i = blockIdx.x * blockDim.x + threadIdx.x;
    int stride = gridDim.x * blockDim.x;
    float4 z = make_float4(0.f, 0.f, 0.f, 0.f);
    for (; i < n4; i += stride) p[i] = z;
}

__global__ void edge_k(const int* __restrict__ row, const float* __restrict__ xarr,
                       const float* __restrict__ table, float* __restrict__ agg, int E) {
    int gid    = blockIdx.x * blockDim.x + threadIdx.x;
    int lane   = gid & 63;
    int wave   = gid >> 6;
    int nwaves = (gridDim.x * blockDim.x) >> 6;
    const float scale = (float)(TN - 1) / (XMAX - XMIN);
    for (int e = wave; e < E; e += nwaves) {
        float x = xarr[e];
        int   r = row[e];
        float t = fminf(fmaxf((x - XMIN) * scale, 0.0f), (float)(TN - 1) - 0.001f);
        int   i0 = (int)t;
        float f  = t - (float)i0;
        const float* tp = table + (size_t)i0 * 64 + lane;
        float v0 = tp[0];
        float v1 = tp[64];
        atomicAdd(agg + (size_t)r * 64 + lane, fmaf(f, v1 - v0, v0));  // global f32: native
    }
}

// ---------------------------------------------------------------------------
extern "C" void kernel_launch(void* const* d_in, const int* in_sizes, int n_in,
                              void* d_out, int out_size, void* d_ws, size_t ws_size,
                              hipStream_t stream) {
    const int*   edge_index = (const int*)  d_in[0];   // [2, E] int32; row = first E
    const float* edge_attr  = (const float*)d_in[1];   // [E, 1]
    const float* W1 = (const float*)d_in[2];
    const float* b1 = (const float*)d_in[3];
    const float* W2 = (const float*)d_in[4];
    const float* b2 = (const float*)d_in[5];
    const float* W3 = (const float*)d_in[6];
    const float* b3 = (const float*)d_in[7];
    const float* W4 = (const float*)d_in[8];
    const float* b4 = (const float*)d_in[9];

    float* out = (float*)d_out;                        // [N, 64]
    const int E   = in_sizes[1];
    const int N   = out_size / 64;
    const int nbk = (N + 127) >> 7;                    // 782 buckets of 128 nodes
    const int M   = nbk * GB1;
    const int nsb = (M + S2_ELEMS - 1) / S2_ELEMS;
    const int nmb = (N + 63) / 64;                     // mlp blocks

    // workspace carve-up (256 B aligned)
    char* ws = (char*)d_ws;
    size_t off = 0;
    auto carve = [&](size_t bytes) { size_t r = off; off = (off + bytes + 255) & ~(size_t)255; return r; };
    size_t tableOff = carve((size_t)TN * 64 * 4);      // 1 MiB
    size_t bhOff    = carve((size_t)M * 4);            // ~800 KiB
    size_t bsumOff  = carve((size_t)nsb * 4);
    size_t pkOff    = carve((size_t)E * 4);            // 6.4 MiB
    bool fits = (off <= ws_size) && (nbk <= MAXBK) && (nsb <= 256);

    float* table = (float*)(ws + tableOff);

    build_table_k<<<TN / 4, 256, 0, stream>>>(W1, b1, W2, b2, table);

    if (fits) {
        int* bh   = (int*)(ws + bhOff);
        int* bsum = (int*)(ws + bsumOff);
        unsigned int* packed = (unsigned int*)(ws + pkOff);

        bhist_k  <<<GB1, 256, 0, stream>>>(edge_index, bh, E, nbk);
        scan2A_k <<<nsb, S2_BS, 0, stream>>>(bh, bh, bsum, M);
        scanB_k  <<<1, 256, 0, stream>>>(bsum, nsb);
        scan2C_k <<<(M + 255) / 256, 256, 0, stream>>>(bh, bsum, M);
        bscatter_k<<<GB1, 256, 0, stream>>>(edge_index, edge_attr, bh, packed, E, nbk);
        gather_k <<<nbk, 256, 0, stream>>>(packed, bh, table, out, N, E, nbk);
        mlp_k    <<<nmb, 256, 0, stream>>>(W3, b3, W4, b4, out, N);
    } else {
        zero_k<<<4096, 256, 0, stream>>>((float4*)out, (N * 64) / 4);
        edge_k<<<8192, 256, 0, stream>>>(edge_index, edge_attr, table, out, E);
        mlp_k <<<nmb, 256, 0, stream>>>(W3, b3, W4, b4, out, N);
    }
}